// Round 4
// baseline (299.698 us; speedup 1.0000x reference)
//
#include <hip/hip_runtime.h>
#include <hip/hip_fp16.h>

#define N_NODES 100000
#define N_EDGES 1600000
#define BSHIFT 9
#define NBUCK ((N_NODES + 511) / 512)   // 196 coarse buckets of 512 nodes
#define BCAP 12288                      // per-bucket capacity (mean 8163, ~45 sigma)

// ---------------------------------------------------------------------------
// phase 1: bucket edges by dst>>9. Entry packed: src | (dst&511)<<17.
__global__ void bucket1_kernel(const int* __restrict__ src, const int* __restrict__ dst,
                               int* __restrict__ gbcount, int* __restrict__ bbuf, int E) {
    __shared__ int hcnt[NBUCK];
    __shared__ int hbase[NBUCK];
    int t = threadIdx.x;
    for (int i = t; i < NBUCK; i += 256) hcnt[i] = 0;
    __syncthreads();
    int e0 = blockIdx.x * 2048 + t;
    int ss[8], dd[8];
#pragma unroll
    for (int u = 0; u < 8; u++) {
        int e = e0 + u * 256;
        if (e < E) {
            ss[u] = src[e];
            dd[u] = dst[e];
            atomicAdd(&hcnt[dd[u] >> BSHIFT], 1);
        } else {
            dd[u] = -1;
        }
    }
    __syncthreads();
    for (int i = t; i < NBUCK; i += 256) {
        int c = hcnt[i];
        hbase[i] = c ? atomicAdd(&gbcount[i], c) : 0;
        hcnt[i] = 0;   // reuse as local cursor
    }
    __syncthreads();
#pragma unroll
    for (int u = 0; u < 8; u++) {
        if (dd[u] >= 0) {
            int bk = dd[u] >> BSHIFT;
            int r = atomicAdd(&hcnt[bk], 1);
            bbuf[(size_t)bk * BCAP + hbase[bk] + r] = ss[u] | ((dd[u] & 511) << 17);
        }
    }
}

// --- exclusive scan of the 196 bucket sizes -> bucket bases; rowptr[N]=E ----
__global__ void scan196_kernel(const int* __restrict__ gbcount, int* __restrict__ gbase,
                               int* __restrict__ rowptrN, int E) {
    __shared__ int s[256];
    int t = threadIdx.x;
    int v = (t < NBUCK) ? gbcount[t] : 0;
    s[t] = v;
    __syncthreads();
    for (int off = 1; off < 256; off <<= 1) {
        int u = (t >= off) ? s[t - off] : 0;
        __syncthreads();
        s[t] += u;
        __syncthreads();
    }
    if (t < NBUCK) gbase[t] = s[t] - v;
    if (t == 0) *rowptrN = E;
}

// --- phase 2 (fused hist+scan+dinv+scatter): one 512-thread block per bucket.
__global__ __launch_bounds__(512)
void bucket2_kernel(const int* __restrict__ bbuf, const int* __restrict__ gbcount,
                    const int* __restrict__ gbase, int* __restrict__ rowptr,
                    float* __restrict__ dinv, int* __restrict__ eidx, int N) {
    int b = blockIdx.x;
    int base_node = b << BSHIFT;
    int nn = min(512, N - base_node);
    int t = threadIdx.x;
    __shared__ int s[512];
    __shared__ int cur[512];
    s[t] = 0;
    __syncthreads();
    int sz = gbcount[b];
    const int* eb = bbuf + (size_t)b * BCAP;
    for (int j = t; j < sz; j += 512) atomicAdd(&s[((unsigned)eb[j]) >> 17], 1);
    __syncthreads();
    int myc = s[t];
    if (t < nn) dinv[base_node + t] = rsqrtf((float)myc + 1.0f);
    __syncthreads();
    for (int off = 1; off < 512; off <<= 1) {
        int u = (t >= off) ? s[t - off] : 0;
        __syncthreads();
        s[t] += u;
        __syncthreads();
    }
    int rp = gbase[b] + s[t] - myc;      // exclusive
    if (t < nn) rowptr[base_node + t] = rp;
    cur[t] = rp;
    __syncthreads();
    for (int j = t; j < sz; j += 512) {
        int e = eb[j];
        int pos = atomicAdd(&cur[((unsigned)e) >> 17], 1);
        eidx[pos] = e & 0x1FFFF;
    }
}

// --- determinism: canonicalize each row (sort ascending). One WAVE per row. --
__global__ void sortrow_wave(const int* __restrict__ rowptr, int* __restrict__ eidx, int n) {
    int g = (blockIdx.x * blockDim.x + threadIdx.x) >> 6;
    int lane = threadIdx.x & 63;
    if (g >= n) return;
    int start = rowptr[g];
    int end = rowptr[g + 1];
    int len = end - start;
    if (len <= 1) return;

    if (len <= 64) {
        int v = (lane < len) ? eidx[start + lane] : 0x7fffffff;
#pragma unroll
        for (int k = 2; k <= 64; k <<= 1) {
#pragma unroll
            for (int j = k >> 1; j > 0; j >>= 1) {
                int partner = __shfl_xor(v, j, 64);
                bool up = ((lane & k) == 0);
                bool keepMin = (((lane & j) == 0) == up);
                int mn = min(v, partner), mx = max(v, partner);
                v = keepMin ? mn : mx;
            }
        }
        if (lane < len) eidx[start + lane] = v;
    } else if (lane == 0) {
        for (int i = start + 1; i < end; i++) {
            int key = eidx[i];
            int j = i - 1;
            while (j >= start && eidx[j] > key) { eidx[j + 1] = eidx[j]; j--; }
            eidx[j + 1] = key;
        }
    }
}

// ---------------------------------------------------------------------------
// LDS-tiled GEMM, 4x4 register blocking, epilogue = dinv * fp16, written into
// FEATURE-SLICED tables: slice s (16 cols) is a contiguous N x 16 fp16 table at
// out + s*n*16. R19: slicing makes each gather table 3.2 MB -> L2-resident.
template <int FIN, int FOUT>
__global__ __launch_bounds__(256, 2)
void gemm_tiled(const float* __restrict__ in, const float* __restrict__ W,
                const float* __restrict__ dinv, __half* __restrict__ out, int n) {
    constexpr int CG = FOUT / 4;
    constexpr int RG = 256 / CG;
    constexpr int TR = RG * 4;
    constexpr int LDA = FIN + 4;
    __shared__ float sIn[TR * LDA];
    __shared__ float sW[FIN * FOUT];

    for (int i = threadIdx.x; i < FIN * FOUT / 4; i += 256)
        ((float4*)sW)[i] = ((const float4*)W)[i];

    int r0 = blockIdx.x * TR;
    for (int i = threadIdx.x; i < TR * FIN / 4; i += 256) {
        int rr = i / (FIN / 4);
        int cc = i % (FIN / 4);
        int gr = r0 + rr;
        float4 v = (gr < n) ? ((const float4*)in)[(size_t)gr * (FIN / 4) + cc]
                            : make_float4(0.f, 0.f, 0.f, 0.f);
        *(float4*)&sIn[rr * LDA + cc * 4] = v;
    }
    __syncthreads();

    int tc = threadIdx.x % CG;
    int tr = threadIdx.x / CG;
    int rbase = tr * 4, cbase = tc * 4;
    float acc[4][4] = {};

#pragma unroll 2
    for (int k = 0; k < FIN; k += 4) {
        float4 a[4], b[4];
#pragma unroll
        for (int i = 0; i < 4; i++) a[i] = *(float4*)&sIn[(rbase + i) * LDA + k];
#pragma unroll
        for (int kk = 0; kk < 4; kk++) b[kk] = *(float4*)&sW[(k + kk) * FOUT + cbase];
#pragma unroll
        for (int i = 0; i < 4; i++) {
            acc[i][0] += a[i].x * b[0].x + a[i].y * b[1].x + a[i].z * b[2].x + a[i].w * b[3].x;
            acc[i][1] += a[i].x * b[0].y + a[i].y * b[1].y + a[i].z * b[2].y + a[i].w * b[3].y;
            acc[i][2] += a[i].x * b[0].z + a[i].y * b[1].z + a[i].z * b[2].z + a[i].w * b[3].z;
            acc[i][3] += a[i].x * b[0].w + a[i].y * b[1].w + a[i].z * b[2].w + a[i].w * b[3].w;
        }
    }

    int slice = cbase >> 4;          // 16-col slice index
    int cw = cbase & 15;             // col within slice
    __half* obase = out + (size_t)slice * ((size_t)n * 16);
#pragma unroll
    for (int i = 0; i < 4; i++) {
        int gr = r0 + rbase + i;
        if (gr < n) {
            float dv = dinv[gr];
            union { __half h[4]; uint2 u; } pk;
            pk.h[0] = __float2half_rn(dv * acc[i][0]);
            pk.h[1] = __float2half_rn(dv * acc[i][1]);
            pk.h[2] = __float2half_rn(dv * acc[i][2]);
            pk.h[3] = __float2half_rn(dv * acc[i][3]);
            *(uint2*)&obase[(size_t)gr * 16 + cw] = pk.u;
        }
    }
}

// ---------------------------------------------------------------------------
// R19: feature-sliced aggregation. Table = NSLICE tables of N x 16 fp16
// (3.2 MB each, fits a 4 MB XCD L2). slice = (blockIdx&7)>>LOGX pins each
// slice to a fixed XCD group via the %8 round-robin dispatch mapping, so each
// XCD's L2 permanently holds its slice -> gathers are ~all L2 hits.
// L=2 lanes/node, 32 nodes/wave: 4x fewer wave-instrs/edge than L=8, and
// 8 edges x 32 groups = 256 rows in flight per wave (4x MLP).
// Output: sv[g*SVSTR + slice*16 + f] = relu(di*(agg+self)+bias)  (fp32, so
// rounding points are unchanged vs the fused version: only A1/A2 are fp16).
template <int SVSTR, int LOGX>
__global__ __launch_bounds__(256, 4)
void agg_slice_kernel(const __half* __restrict__ tbl, const int* __restrict__ eidx,
                      const int* __restrict__ rowptr, const float* __restrict__ dinv,
                      const float* __restrict__ bias, float* __restrict__ sv, int n) {
    constexpr int SF = 16;             // features per slice
    constexpr int L = 2;               // lanes per node (8 halves = 16 B each)
    constexpr int NPB = 256 / L;       // 128 nodes per block
    using vh = _Float16 __attribute__((ext_vector_type(8)));

    int blk = blockIdx.x;
    int slice = (blk & 7) >> LOGX;
    int nb = ((blk >> 3) << LOGX) | (blk & ((1 << LOGX) - 1));
    int g = nb * NPB + (int)(threadIdx.x / L);
    if (g >= n) return;
    int lane = threadIdx.x & (L - 1);

    const __half* hb = tbl + (size_t)slice * ((size_t)n * SF) + lane * 8;
    int j = rowptr[g];
    int end = rowptr[g + 1];
    float di = dinv[g];

    float acc0[8], acc1[8];
#pragma unroll
    for (int q = 0; q < 8; q++) { acc0[q] = 0.f; acc1[q] = 0.f; }

    for (; j + 8 <= end; j += 8) {
        int s0 = eidx[j];
        int s1 = eidx[j + 1];
        int s2 = eidx[j + 2];
        int s3 = eidx[j + 3];
        int s4 = eidx[j + 4];
        int s5 = eidx[j + 5];
        int s6 = eidx[j + 6];
        int s7 = eidx[j + 7];
        vh v0 = *(const vh*)(hb + (size_t)s0 * SF);
        vh v1 = *(const vh*)(hb + (size_t)s1 * SF);
        vh v2 = *(const vh*)(hb + (size_t)s2 * SF);
        vh v3 = *(const vh*)(hb + (size_t)s3 * SF);
        vh v4 = *(const vh*)(hb + (size_t)s4 * SF);
        vh v5 = *(const vh*)(hb + (size_t)s5 * SF);
        vh v6 = *(const vh*)(hb + (size_t)s6 * SF);
        vh v7 = *(const vh*)(hb + (size_t)s7 * SF);
#pragma unroll
        for (int q = 0; q < 8; q++) {
            acc0[q] += (float)v0[q] + (float)v2[q];
            acc1[q] += (float)v1[q] + (float)v3[q];
            acc0[q] += (float)v4[q] + (float)v6[q];
            acc1[q] += (float)v5[q] + (float)v7[q];
        }
    }
    for (; j + 2 <= end; j += 2) {
        int s0 = eidx[j];
        int s1 = eidx[j + 1];
        vh v0 = *(const vh*)(hb + (size_t)s0 * SF);
        vh v1 = *(const vh*)(hb + (size_t)s1 * SF);
#pragma unroll
        for (int q = 0; q < 8; q++) { acc0[q] += (float)v0[q]; acc1[q] += (float)v1[q]; }
    }
    if (j < end) {
        vh v = *(const vh*)(hb + (size_t)eidx[j] * SF);
#pragma unroll
        for (int q = 0; q < 8; q++) acc0[q] += (float)v[q];
    }

    vh sf_ = *(const vh*)(hb + (size_t)g * SF);
    const float* bp = bias + slice * SF + lane * 8;
    float r[8];
#pragma unroll
    for (int q = 0; q < 8; q++) {
        float v = di * ((acc0[q] + acc1[q]) + (float)sf_[q]) + bp[q];
        r[q] = fmaxf(v, 0.f);
    }
    float* op = sv + (size_t)g * SVSTR + slice * SF + lane * 8;
    *(float4*)op = make_float4(r[0], r[1], r[2], r[3]);
    *(float4*)(op + 4) = make_float4(r[4], r[5], r[6], r[7]);
}

// ---------------------------------------------------------------------------
// gemm3: A3 = fp32(di * (SV2 @ W3)), N x 32 @ 32 x 2. Streaming, tiny.
__global__ void gemm3_kernel(const float* __restrict__ sv2, const float* __restrict__ W3,
                             const float* __restrict__ dinv, float* __restrict__ A3, int n) {
    __shared__ float sW[64];
    if (threadIdx.x < 64) sW[threadIdx.x] = W3[threadIdx.x];
    __syncthreads();
    int g = blockIdx.x * 256 + threadIdx.x;
    if (g >= n) return;
    const float4* r = (const float4*)(sv2 + (size_t)g * 32);
    float c0 = 0.f, c1 = 0.f;
#pragma unroll
    for (int k4 = 0; k4 < 8; k4++) {
        float4 v = r[k4];
        int k = k4 * 4;
        c0 += v.x * sW[(k + 0) * 2] + v.y * sW[(k + 1) * 2] + v.z * sW[(k + 2) * 2] + v.w * sW[(k + 3) * 2];
        c1 += v.x * sW[(k + 0) * 2 + 1] + v.y * sW[(k + 1) * 2 + 1] + v.z * sW[(k + 2) * 2 + 1] + v.w * sW[(k + 3) * 2 + 1];
    }
    float di = dinv[g];
    float2 o; o.x = di * c0; o.y = di * c1;
    ((float2*)A3)[g] = o;
}

// fp32 gather agg for the final layer (F=2), bias, no relu. A3 table is
// 800 KB -> L2-resident everywhere already. One thread per node, float2 rows.
__global__ void agg2_kernel(const int* __restrict__ eidx, const int* __restrict__ rowptr,
                            const float* __restrict__ dinv, const float* __restrict__ h,
                            const float* __restrict__ b, float* __restrict__ out, int n) {
    int g = blockIdx.x * blockDim.x + threadIdx.x;
    if (g >= n) return;
    const float2* h2 = (const float2*)h;
    int j = rowptr[g];
    int end = rowptr[g + 1];
    float di = dinv[g];
    float2 hs = h2[g];

    float2 a0 = {0.f, 0.f}, a1 = {0.f, 0.f}, a2 = {0.f, 0.f}, a3 = {0.f, 0.f};
    float2 a4 = {0.f, 0.f}, a5 = {0.f, 0.f}, a6 = {0.f, 0.f}, a7 = {0.f, 0.f};
    for (; j + 8 <= end; j += 8) {
        int s0 = eidx[j];
        int s1 = eidx[j + 1];
        int s2 = eidx[j + 2];
        int s3 = eidx[j + 3];
        int s4 = eidx[j + 4];
        int s5 = eidx[j + 5];
        int s6 = eidx[j + 6];
        int s7 = eidx[j + 7];
        float2 v0 = h2[s0]; float2 v1 = h2[s1];
        float2 v2 = h2[s2]; float2 v3 = h2[s3];
        float2 v4 = h2[s4]; float2 v5 = h2[s5];
        float2 v6 = h2[s6]; float2 v7 = h2[s7];
        a0.x += v0.x; a0.y += v0.y;  a1.x += v1.x; a1.y += v1.y;
        a2.x += v2.x; a2.y += v2.y;  a3.x += v3.x; a3.y += v3.y;
        a4.x += v4.x; a4.y += v4.y;  a5.x += v5.x; a5.y += v5.y;
        a6.x += v6.x; a6.y += v6.y;  a7.x += v7.x; a7.y += v7.y;
    }
    for (; j + 2 <= end; j += 2) {
        float2 v0 = h2[eidx[j]];
        float2 v1 = h2[eidx[j + 1]];
        a0.x += v0.x; a0.y += v0.y;
        a1.x += v1.x; a1.y += v1.y;
    }
    if (j < end) {
        float2 v = h2[eidx[j]];
        a2.x += v.x; a2.y += v.y;
    }
    float accx = ((a0.x + a1.x) + (a2.x + a3.x)) + ((a4.x + a5.x) + (a6.x + a7.x));
    float accy = ((a0.y + a1.y) + (a2.y + a3.y)) + ((a4.y + a5.y) + (a6.y + a7.y));
    float2 r;
    r.x = di * (accx + hs.x) + b[0];
    r.y = di * (accy + hs.y) + b[1];
    ((float2*)out)[g] = r;
}

// ---------------------------------------------------------------------------
extern "C" void kernel_launch(void* const* d_in, const int* in_sizes, int n_in,
                              void* d_out, int out_size, void* d_ws, size_t ws_size,
                              hipStream_t stream) {
    const float* x  = (const float*)d_in[0];
    const int* ei   = (const int*)d_in[1];
    const float* W1 = (const float*)d_in[2];
    const float* b1 = (const float*)d_in[3];
    const float* W2 = (const float*)d_in[4];
    const float* b2 = (const float*)d_in[5];
    const float* W3 = (const float*)d_in[6];
    const float* b3 = (const float*)d_in[7];
    float* out = (float*)d_out;

    const int N = N_NODES;
    const int E = N_EDGES;
    const int* src = ei;
    const int* dst = ei + E;

    // Workspace with lifetime overlays:
    //   region X: bbuf (bucket1->bucket2)  /  SV1 fp32 NxM64 (agg1->gemm2)
    //   region Y: A1 4-slice fp16 (gemm1->agg1) / SV2 fp32 Nx32 (agg2s->gemm3)
    char* p = (char*)d_ws;
    int*    rowptr  = (int*)p;            p += ((size_t)(N + 1) * 4 + 15) / 16 * 16;
    float*  dinv    = (float*)p;          p += ((size_t)N * 4 + 15) / 16 * 16;
    int*    gbcount = (int*)p;            p += ((size_t)NBUCK * 4 + 15) / 16 * 16;
    int*    gbase   = (int*)p;            p += ((size_t)NBUCK * 4 + 15) / 16 * 16;
    int*    eidx    = (int*)p;            p += (size_t)E * 4;
    __half* A2      = (__half*)p;         p += (size_t)N * 32 * 2;   // 2 slice tables N x 16
    float*  A3      = (float*)p;          p += (size_t)N * 2 * 4;
    float*  SV1     = (float*)p;
    int*    bbuf    = (int*)p;            p += (size_t)N * 64 * 4;   // max(9.6 MB bbuf, 25.6 MB SV1)
    __half* A1      = (__half*)p;                                    // 4 slice tables N x 16 (12.8 MB)
    float*  SV2     = (float*)p;                                     // N x 32 fp32 (12.8 MB) — same region

    const int T = 256;

    // --- build CSR + dinv: bucket -> scan196 -> fused hist/scan/scatter; sort ---
    hipMemsetAsync(gbcount, 0, NBUCK * sizeof(int), stream);
    bucket1_kernel<<<(E + 2047) / 2048, T, 0, stream>>>(src, dst, gbcount, bbuf, E);
    scan196_kernel<<<1, 256, 0, stream>>>(gbcount, gbase, rowptr + N, E);
    bucket2_kernel<<<NBUCK, 512, 0, stream>>>(bbuf, gbcount, gbase, rowptr, dinv, eidx, N);
    sortrow_wave<<<(N * 64 + T - 1) / T, T, 0, stream>>>(rowptr, eidx, N);

    // --- layer 1 GEMM: A1 (4 slice tables) = fp16(dinv * (x @ W1)) ---
    gemm_tiled<64, 64><<<(N + 63) / 64, T, 0, stream>>>(x, W1, dinv, A1, N);

    // --- agg1 (sliced, XCD-pinned): SV1 = relu(di*(agg(A1)+self)+b1), fp32 Nx64 ---
    int bps1 = (N + 127) / 128;                      // 782 (even)
    agg_slice_kernel<64, 1><<<(bps1 / 2) * 8, T, 0, stream>>>(
        A1, eidx, rowptr, dinv, b1, SV1, N);

    // --- gemm2: A2 (2 slice tables) = fp16(di * (SV1 @ W2)) ---
    gemm_tiled<64, 32><<<(N + 127) / 128, T, 0, stream>>>(SV1, W2, dinv, A2, N);

    // --- agg2 (sliced, XCD-pinned): SV2 = relu(di*(agg(A2)+self)+b2), fp32 Nx32 ---
    agg_slice_kernel<32, 2><<<((bps1 + 3) / 4) * 8, T, 0, stream>>>(
        A2, eidx, rowptr, dinv, b2, SV2, N);

    // --- gemm3: A3 = fp32(di * (SV2 @ W3)) ---
    gemm3_kernel<<<(N + 255) / 256, T, 0, stream>>>(SV2, W3, dinv, A3, N);

    // --- final aggregation: out = dinv*(agg(A3)+self) + b3 ---
    agg2_kernel<<<(N + T - 1) / T, T, 0, stream>>>(eidx, rowptr, dinv, A3, b3, out, N);
}

// Round 5
// 275.691 us; speedup vs baseline: 1.0871x; 1.0871x over previous
//
#include <hip/hip_runtime.h>
#include <hip/hip_fp16.h>

#define N_NODES 100000
#define N_EDGES 1600000
#define BSHIFT 8
#define NBUCK ((N_NODES + 255) / 256)   // 391 buckets of 256 nodes (R20: was 196x512 — 0.77 blocks/CU starved bucket2)
#define BCAP 6144                       // per-bucket capacity (mean 4092, ~32 sigma); 391*6144 <= old 196*12288 footprint

// ---------------------------------------------------------------------------
// phase 1: bucket edges by dst>>8. Entry packed: src | (dst&255)<<17.
__global__ void bucket1_kernel(const int* __restrict__ src, const int* __restrict__ dst,
                               int* __restrict__ gbcount, int* __restrict__ bbuf, int E) {
    __shared__ int hcnt[NBUCK];
    __shared__ int hbase[NBUCK];
    int t = threadIdx.x;
    for (int i = t; i < NBUCK; i += 256) hcnt[i] = 0;
    __syncthreads();
    int e0 = blockIdx.x * 2048 + t;
    int ss[8], dd[8];
#pragma unroll
    for (int u = 0; u < 8; u++) {
        int e = e0 + u * 256;
        if (e < E) {
            ss[u] = src[e];
            dd[u] = dst[e];
            atomicAdd(&hcnt[dd[u] >> BSHIFT], 1);
        } else {
            dd[u] = -1;
        }
    }
    __syncthreads();
    for (int i = t; i < NBUCK; i += 256) {
        int c = hcnt[i];
        hbase[i] = c ? atomicAdd(&gbcount[i], c) : 0;
        hcnt[i] = 0;   // reuse as local cursor
    }
    __syncthreads();
#pragma unroll
    for (int u = 0; u < 8; u++) {
        if (dd[u] >= 0) {
            int bk = dd[u] >> BSHIFT;
            int r = atomicAdd(&hcnt[bk], 1);
            bbuf[(size_t)bk * BCAP + hbase[bk] + r] = ss[u] | ((dd[u] & 255) << 17);
        }
    }
}

// --- exclusive scan of the 391 bucket sizes -> bucket bases; rowptr[N]=E ----
__global__ __launch_bounds__(512)
void scan_buckets_kernel(const int* __restrict__ gbcount, int* __restrict__ gbase,
                         int* __restrict__ rowptrN, int E) {
    __shared__ int s[512];
    int t = threadIdx.x;
    int v = (t < NBUCK) ? gbcount[t] : 0;
    s[t] = v;
    __syncthreads();
    for (int off = 1; off < 512; off <<= 1) {
        int u = (t >= off) ? s[t - off] : 0;
        __syncthreads();
        s[t] += u;
        __syncthreads();
    }
    if (t < NBUCK) gbase[t] = s[t] - v;
    if (t == 0) *rowptrN = E;
}

// --- phase 2 (fused hist+scan+dinv+scatter): one 512-thread block per bucket
// of 256 nodes. 391 blocks (was 196) -> better chip fill; half work per block.
__global__ __launch_bounds__(512)
void bucket2_kernel(const int* __restrict__ bbuf, const int* __restrict__ gbcount,
                    const int* __restrict__ gbase, int* __restrict__ rowptr,
                    float* __restrict__ dinv, int* __restrict__ eidx, int N) {
    int b = blockIdx.x;
    int base_node = b << BSHIFT;
    int nn = min(256, N - base_node);
    int t = threadIdx.x;
    __shared__ int s[256];
    __shared__ int cur[256];
    if (t < 256) s[t] = 0;
    __syncthreads();
    int sz = gbcount[b];
    const int* eb = bbuf + (size_t)b * BCAP;
    for (int j = t; j < sz; j += 512) atomicAdd(&s[((unsigned)eb[j]) >> 17], 1);
    __syncthreads();
    int myc = (t < 256) ? s[t] : 0;
    if (t < nn) dinv[base_node + t] = rsqrtf((float)myc + 1.0f);
    __syncthreads();
    for (int off = 1; off < 256; off <<= 1) {
        int u = (t >= off && t < 256) ? s[t - off] : 0;
        __syncthreads();
        if (t < 256) s[t] += u;
        __syncthreads();
    }
    if (t < 256) {
        int rp = gbase[b] + s[t] - myc;  // exclusive
        if (t < nn) rowptr[base_node + t] = rp;
        cur[t] = rp;
    }
    __syncthreads();
    for (int j = t; j < sz; j += 512) {
        int e = eb[j];
        int pos = atomicAdd(&cur[((unsigned)e) >> 17], 1);
        eidx[pos] = e & 0x1FFFF;
    }
}

// --- determinism: canonicalize each row (sort ascending). One WAVE per row. --
__global__ void sortrow_wave(const int* __restrict__ rowptr, int* __restrict__ eidx, int n) {
    int g = (blockIdx.x * blockDim.x + threadIdx.x) >> 6;
    int lane = threadIdx.x & 63;
    if (g >= n) return;
    int start = rowptr[g];
    int end = rowptr[g + 1];
    int len = end - start;
    if (len <= 1) return;

    if (len <= 64) {
        int v = (lane < len) ? eidx[start + lane] : 0x7fffffff;
#pragma unroll
        for (int k = 2; k <= 64; k <<= 1) {
#pragma unroll
            for (int j = k >> 1; j > 0; j >>= 1) {
                int partner = __shfl_xor(v, j, 64);
                bool up = ((lane & k) == 0);
                bool keepMin = (((lane & j) == 0) == up);
                int mn = min(v, partner), mx = max(v, partner);
                v = keepMin ? mn : mx;
            }
        }
        if (lane < len) eidx[start + lane] = v;
    } else if (lane == 0) {
        for (int i = start + 1; i < end; i++) {
            int key = eidx[i];
            int j = i - 1;
            while (j >= start && eidx[j] > key) { eidx[j + 1] = eidx[j]; j--; }
            eidx[j + 1] = key;
        }
    }
}

// ---------------------------------------------------------------------------
// LDS-tiled GEMM (layer 1 only), 4x4 register blocking, epilogue = dinv*fp16.
template <int FIN, int FOUT>
__global__ __launch_bounds__(256, 2)
void gemm_tiled(const float* __restrict__ in, const float* __restrict__ W,
                const float* __restrict__ dinv, __half* __restrict__ out, int n) {
    constexpr int CG = FOUT / 4;
    constexpr int RG = 256 / CG;
    constexpr int TR = RG * 4;
    constexpr int LDA = FIN + 4;
    __shared__ float sIn[TR * LDA];
    __shared__ float sW[FIN * FOUT];

    for (int i = threadIdx.x; i < FIN * FOUT / 4; i += 256)
        ((float4*)sW)[i] = ((const float4*)W)[i];

    int r0 = blockIdx.x * TR;
    for (int i = threadIdx.x; i < TR * FIN / 4; i += 256) {
        int rr = i / (FIN / 4);
        int cc = i % (FIN / 4);
        int gr = r0 + rr;
        float4 v = (gr < n) ? ((const float4*)in)[(size_t)gr * (FIN / 4) + cc]
                            : make_float4(0.f, 0.f, 0.f, 0.f);
        *(float4*)&sIn[rr * LDA + cc * 4] = v;
    }
    __syncthreads();

    int tc = threadIdx.x % CG;
    int tr = threadIdx.x / CG;
    int rbase = tr * 4, cbase = tc * 4;
    float acc[4][4] = {};

#pragma unroll 2
    for (int k = 0; k < FIN; k += 4) {
        float4 a[4], b[4];
#pragma unroll
        for (int i = 0; i < 4; i++) a[i] = *(float4*)&sIn[(rbase + i) * LDA + k];
#pragma unroll
        for (int kk = 0; kk < 4; kk++) b[kk] = *(float4*)&sW[(k + kk) * FOUT + cbase];
#pragma unroll
        for (int i = 0; i < 4; i++) {
            acc[i][0] += a[i].x * b[0].x + a[i].y * b[1].x + a[i].z * b[2].x + a[i].w * b[3].x;
            acc[i][1] += a[i].x * b[0].y + a[i].y * b[1].y + a[i].z * b[2].y + a[i].w * b[3].y;
            acc[i][2] += a[i].x * b[0].z + a[i].y * b[1].z + a[i].z * b[2].z + a[i].w * b[3].z;
            acc[i][3] += a[i].x * b[0].w + a[i].y * b[1].w + a[i].z * b[2].w + a[i].w * b[3].w;
        }
    }

#pragma unroll
    for (int i = 0; i < 4; i++) {
        int gr = r0 + rbase + i;
        if (gr < n) {
            float dv = dinv[gr];
            union { __half h[4]; uint2 u; } pk;
            pk.h[0] = __float2half_rn(dv * acc[i][0]);
            pk.h[1] = __float2half_rn(dv * acc[i][1]);
            pk.h[2] = __float2half_rn(dv * acc[i][2]);
            pk.h[3] = __float2half_rn(dv * acc[i][3]);
            *(uint2*)&out[(size_t)gr * FOUT + cbase] = pk.u;
        }
    }
}

// ---------------------------------------------------------------------------
// FUSED aggregation + next-layer matvec, layer 2 (FIN=64, FOUT=32). Exact R0
// body (best-measured 52.5us): L=8 lanes/node, 16-B loads, no self-row hoist.
__global__ __launch_bounds__(256, 4)
void agg_gemm64_kernel(const int* __restrict__ eidx, const int* __restrict__ rowptr,
                       const float* __restrict__ dinv, const __half* __restrict__ h,
                       const float* __restrict__ bias, const float* __restrict__ W,
                       __half* __restrict__ out, int n) {
    constexpr int FIN = 64, FOUT = 32;
    constexpr int L = 8;                 // lanes per node
    constexpr int PH = FIN / L;          // 8 halves per lane (16 B)
    constexpr int NODES = 256 / L;       // 32 nodes per block
    constexpr int SVS = FIN + 1;         // padded sv stride (bank-conflict fix)
    using vh = _Float16 __attribute__((ext_vector_type(PH)));
    __shared__ float sW[FIN * FOUT];
    __shared__ float sv[NODES * SVS];

    for (int i = threadIdx.x; i < FIN * FOUT / 4; i += 256)
        ((float4*)sW)[i] = ((const float4*)W)[i];

    int g = (blockIdx.x * blockDim.x + threadIdx.x) / L;
    int lane = threadIdx.x % L;
    int slot = threadIdx.x / L;          // node slot in block
    float di = 0.f;

    if (g < n) {
        int j = rowptr[g];
        int end = rowptr[g + 1];
        di = dinv[g];
        const __half* hb = h + lane * PH;

        float acc0[PH], acc1[PH];
#pragma unroll
        for (int q = 0; q < PH; q++) { acc0[q] = 0.f; acc1[q] = 0.f; }

        for (; j + 8 <= end; j += 8) {
            int s0 = eidx[j];
            int s1 = eidx[j + 1];
            int s2 = eidx[j + 2];
            int s3 = eidx[j + 3];
            int s4 = eidx[j + 4];
            int s5 = eidx[j + 5];
            int s6 = eidx[j + 6];
            int s7 = eidx[j + 7];
            vh v0 = *(const vh*)(hb + (size_t)s0 * FIN);
            vh v1 = *(const vh*)(hb + (size_t)s1 * FIN);
            vh v2 = *(const vh*)(hb + (size_t)s2 * FIN);
            vh v3 = *(const vh*)(hb + (size_t)s3 * FIN);
            vh v4 = *(const vh*)(hb + (size_t)s4 * FIN);
            vh v5 = *(const vh*)(hb + (size_t)s5 * FIN);
            vh v6 = *(const vh*)(hb + (size_t)s6 * FIN);
            vh v7 = *(const vh*)(hb + (size_t)s7 * FIN);
#pragma unroll
            for (int q = 0; q < PH; q++) {
                acc0[q] += (float)v0[q] + (float)v2[q];
                acc1[q] += (float)v1[q] + (float)v3[q];
                acc0[q] += (float)v4[q] + (float)v6[q];
                acc1[q] += (float)v5[q] + (float)v7[q];
            }
        }
        for (; j + 2 <= end; j += 2) {
            int s0 = eidx[j];
            int s1 = eidx[j + 1];
            vh v0 = *(const vh*)(hb + (size_t)s0 * FIN);
            vh v1 = *(const vh*)(hb + (size_t)s1 * FIN);
#pragma unroll
            for (int q = 0; q < PH; q++) { acc0[q] += (float)v0[q]; acc1[q] += (float)v1[q]; }
        }
        if (j < end) {
            vh v = *(const vh*)(hb + (size_t)eidx[j] * FIN);
#pragma unroll
            for (int q = 0; q < PH; q++) acc0[q] += (float)v[q];
        }

        vh sf = *(const vh*)(hb + (size_t)g * FIN);
        float* svn = &sv[slot * SVS + lane * PH];
#pragma unroll
        for (int q = 0; q < PH; q++) {
            float v = di * ((acc0[q] + acc1[q]) + (float)sf[q]) + bias[lane * PH + q];
            svn[q] = fmaxf(v, 0.f);      // relu
        }
    }
    __syncthreads();                     // sW loaded + sv written

    if (g < n) {
        const float* vn = &sv[slot * SVS];
        constexpr int PC = FOUT / L;     // 4 output cols per lane
        float o[PC] = {};
        for (int k = 0; k < FIN; k++) {
            float vk = vn[k];
            float4 w = *(const float4*)&sW[k * FOUT + lane * PC];
            o[0] += vk * w.x; o[1] += vk * w.y; o[2] += vk * w.z; o[3] += vk * w.w;
        }
        union { __half h2[4]; uint2 u; } pk;
#pragma unroll
        for (int q = 0; q < PC; q++) pk.h2[q] = __float2half_rn(di * o[q]);
        *(uint2*)&out[(size_t)g * FOUT + lane * PC] = pk.u;
    }
}

// ---------------------------------------------------------------------------
// R20: fused agg + matvec, layer 3 (FIN=32, FOUT=2), L=4 lanes/node with 16-B
// loads (was L=8 with 8-B): halves gather wave-instructions per edge while
// keeping 6250 waves (24/CU) resident. Per-feature summation order (edge ->
// acc0/acc1 mapping, ascending j) is bitwise-identical to the L=8 version.
__global__ __launch_bounds__(256, 4)
void agg_gemm32_kernel(const int* __restrict__ eidx, const int* __restrict__ rowptr,
                       const float* __restrict__ dinv, const __half* __restrict__ h,
                       const float* __restrict__ bias, const float* __restrict__ W,
                       float* __restrict__ out, int n) {
    constexpr int FIN = 32, FOUT = 2;
    constexpr int L = 4;                 // lanes per node
    constexpr int PH = FIN / L;          // 8 halves per lane (16 B)
    constexpr int NODES = 256 / L;       // 64 nodes per block
    constexpr int SVS = FIN + 1;         // padded sv stride
    using vh = _Float16 __attribute__((ext_vector_type(PH)));
    __shared__ float sW[FIN * FOUT];     // 64 floats
    __shared__ float sv[NODES * SVS];    // 64*33*4 = 8448 B

    if (threadIdx.x < FIN * FOUT) sW[threadIdx.x] = W[threadIdx.x];

    int g = (blockIdx.x * blockDim.x + threadIdx.x) / L;
    int lane = threadIdx.x % L;
    int slot = threadIdx.x / L;
    float di = 0.f;

    if (g < n) {
        int j = rowptr[g];
        int end = rowptr[g + 1];
        di = dinv[g];
        const __half* hb = h + lane * PH;

        float acc0[PH], acc1[PH];
#pragma unroll
        for (int q = 0; q < PH; q++) { acc0[q] = 0.f; acc1[q] = 0.f; }

        for (; j + 8 <= end; j += 8) {
            int s0 = eidx[j];
            int s1 = eidx[j + 1];
            int s2 = eidx[j + 2];
            int s3 = eidx[j + 3];
            int s4 = eidx[j + 4];
            int s5 = eidx[j + 5];
            int s6 = eidx[j + 6];
            int s7 = eidx[j + 7];
            vh v0 = *(const vh*)(hb + (size_t)s0 * FIN);
            vh v1 = *(const vh*)(hb + (size_t)s1 * FIN);
            vh v2 = *(const vh*)(hb + (size_t)s2 * FIN);
            vh v3 = *(const vh*)(hb + (size_t)s3 * FIN);
            vh v4 = *(const vh*)(hb + (size_t)s4 * FIN);
            vh v5 = *(const vh*)(hb + (size_t)s5 * FIN);
            vh v6 = *(const vh*)(hb + (size_t)s6 * FIN);
            vh v7 = *(const vh*)(hb + (size_t)s7 * FIN);
#pragma unroll
            for (int q = 0; q < PH; q++) {
                acc0[q] += (float)v0[q] + (float)v2[q];
                acc1[q] += (float)v1[q] + (float)v3[q];
                acc0[q] += (float)v4[q] + (float)v6[q];
                acc1[q] += (float)v5[q] + (float)v7[q];
            }
        }
        for (; j + 2 <= end; j += 2) {
            int s0 = eidx[j];
            int s1 = eidx[j + 1];
            vh v0 = *(const vh*)(hb + (size_t)s0 * FIN);
            vh v1 = *(const vh*)(hb + (size_t)s1 * FIN);
#pragma unroll
            for (int q = 0; q < PH; q++) { acc0[q] += (float)v0[q]; acc1[q] += (float)v1[q]; }
        }
        if (j < end) {
            vh v = *(const vh*)(hb + (size_t)eidx[j] * FIN);
#pragma unroll
            for (int q = 0; q < PH; q++) acc0[q] += (float)v[q];
        }

        vh sf = *(const vh*)(hb + (size_t)g * FIN);
        float* svn = &sv[slot * SVS + lane * PH];
#pragma unroll
        for (int q = 0; q < PH; q++) {
            float v = di * ((acc0[q] + acc1[q]) + (float)sf[q]) + bias[lane * PH + q];
            svn[q] = fmaxf(v, 0.f);      // relu
        }
    }
    __syncthreads();                     // sW loaded + sv written

    if (g < n && lane < FOUT) {
        const float* vn = &sv[slot * SVS];
        float o = 0.f;
        for (int k = 0; k < FIN; k++) o += vn[k] * sW[k * FOUT + lane];
        out[(size_t)g * FOUT + lane] = di * o;
    }
}

// fp32 gather agg for the final layer (F=2), bias, no relu.
// One THREAD per node loading float2 rows (halves L2 request count vs the
// 2-lane version). Per-component summation order is bitwise-identical.
__global__ void agg2_kernel(const int* __restrict__ eidx, const int* __restrict__ rowptr,
                            const float* __restrict__ dinv, const float* __restrict__ h,
                            const float* __restrict__ b, float* __restrict__ out, int n) {
    int g = blockIdx.x * blockDim.x + threadIdx.x;
    if (g >= n) return;
    const float2* h2 = (const float2*)h;
    int j = rowptr[g];
    int end = rowptr[g + 1];
    float di = dinv[g];
    float2 hs = h2[g];

    float2 a0 = {0.f, 0.f}, a1 = {0.f, 0.f}, a2 = {0.f, 0.f}, a3 = {0.f, 0.f};
    float2 a4 = {0.f, 0.f}, a5 = {0.f, 0.f}, a6 = {0.f, 0.f}, a7 = {0.f, 0.f};
    for (; j + 8 <= end; j += 8) {
        int s0 = eidx[j];
        int s1 = eidx[j + 1];
        int s2 = eidx[j + 2];
        int s3 = eidx[j + 3];
        int s4 = eidx[j + 4];
        int s5 = eidx[j + 5];
        int s6 = eidx[j + 6];
        int s7 = eidx[j + 7];
        float2 v0 = h2[s0]; float2 v1 = h2[s1];
        float2 v2 = h2[s2]; float2 v3 = h2[s3];
        float2 v4 = h2[s4]; float2 v5 = h2[s5];
        float2 v6 = h2[s6]; float2 v7 = h2[s7];
        a0.x += v0.x; a0.y += v0.y;  a1.x += v1.x; a1.y += v1.y;
        a2.x += v2.x; a2.y += v2.y;  a3.x += v3.x; a3.y += v3.y;
        a4.x += v4.x; a4.y += v4.y;  a5.x += v5.x; a5.y += v5.y;
        a6.x += v6.x; a6.y += v6.y;  a7.x += v7.x; a7.y += v7.y;
    }
    for (; j + 2 <= end; j += 2) {
        float2 v0 = h2[eidx[j]];
        float2 v1 = h2[eidx[j + 1]];
        a0.x += v0.x; a0.y += v0.y;
        a1.x += v1.x; a1.y += v1.y;
    }
    if (j < end) {
        float2 v = h2[eidx[j]];
        a2.x += v.x; a2.y += v.y;
    }
    float accx = ((a0.x + a1.x) + (a2.x + a3.x)) + ((a4.x + a5.x) + (a6.x + a7.x));
    float accy = ((a0.y + a1.y) + (a2.y + a3.y)) + ((a4.y + a5.y) + (a6.y + a7.y));
    float2 r;
    r.x = di * (accx + hs.x) + b[0];
    r.y = di * (accy + hs.y) + b[1];
    ((float2*)out)[g] = r;
}

// ---------------------------------------------------------------------------
extern "C" void kernel_launch(void* const* d_in, const int* in_sizes, int n_in,
                              void* d_out, int out_size, void* d_ws, size_t ws_size,
                              hipStream_t stream) {
    const float* x  = (const float*)d_in[0];
    const int* ei   = (const int*)d_in[1];
    const float* W1 = (const float*)d_in[2];
    const float* b1 = (const float*)d_in[3];
    const float* W2 = (const float*)d_in[4];
    const float* b2 = (const float*)d_in[5];
    const float* W3 = (const float*)d_in[6];
    const float* b3 = (const float*)d_in[7];
    float* out = (float*)d_out;

    const int N = N_NODES;
    const int E = N_EDGES;
    const int* src = ei;
    const int* dst = ei + E;

    char* p = (char*)d_ws;
    int*    rowptr  = (int*)p;            p += ((size_t)(N + 1) * 4 + 15) / 16 * 16;
    float*  dinv    = (float*)p;          p += ((size_t)N * 4 + 15) / 16 * 16;
    int*    gbcount = (int*)p;            p += ((size_t)NBUCK * 4 + 15) / 16 * 16;
    int*    gbase   = (int*)p;            p += ((size_t)NBUCK * 4 + 15) / 16 * 16;
    int*    eidx    = (int*)p;            p += (size_t)E * 4;
    __half* A1      = (__half*)p;         p += (size_t)N * 64 * 2;
    __half* A2      = (__half*)p;         p += (size_t)N * 32 * 2;
    float*  A3      = (float*)p;          p += (size_t)N * 2 * 4;
    int*    bbuf    = (int*)p;            // 391*6144*4 = 9.61 MB (packed edges)

    const int T = 256;

    // --- build CSR + dinv: bucket -> scan -> fused hist/scan/scatter; sort ---
    hipMemsetAsync(gbcount, 0, NBUCK * sizeof(int), stream);
    bucket1_kernel<<<(E + 2047) / 2048, T, 0, stream>>>(src, dst, gbcount, bbuf, E);
    scan_buckets_kernel<<<1, 512, 0, stream>>>(gbcount, gbase, rowptr + N, E);
    bucket2_kernel<<<NBUCK, 512, 0, stream>>>(bbuf, gbcount, gbase, rowptr, dinv, eidx, N);
    sortrow_wave<<<(N * 64 + T - 1) / T, T, 0, stream>>>(rowptr, eidx, N);

    // --- layer 1 GEMM: A1 = fp16(dinv * (x @ W1)) ---
    gemm_tiled<64, 64><<<(N + 63) / 64, T, 0, stream>>>(x, W1, dinv, A1, N);

    // --- fused agg1 + gemm2: A2 = fp16(dinv * relu(agg(A1)+b1) @ W2) ---
    agg_gemm64_kernel<<<(N + 31) / 32, T, 0, stream>>>(
        eidx, rowptr, dinv, A1, b1, W2, A2, N);

    // --- fused agg2 + gemm3: A3 = fp32(dinv * relu(agg(A2)+b2) @ W3) ---
    agg_gemm32_kernel<<<(N + 63) / 64, T, 0, stream>>>(
        eidx, rowptr, dinv, A2, b2, W3, A3, N);

    // --- final aggregation: out = dinv*(agg(A3)+self) + b3 ---
    agg2_kernel<<<(N + T - 1) / T, T, 0, stream>>>(eidx, rowptr, dinv, A3, b3, out, N);
}